// Round 4
// baseline (317.507 us; speedup 1.0000x reference)
//
#include <hip/hip_runtime.h>

// dist[N,K] = ||feat_n||^2 + ||cent_k||^2 - 2 feat . cent
// N=16384, K=2048, D=1024, fp32 in/out.
// bf16 MFMA GEMM: 128x128 tile, BK=64. A staged via global_load_lds (16B) with
// XOR bank swizzle; B (4MB, L2-resident) read per-fragment straight into
// registers at loop top (latency hidden under A-stage + barrier drain).
// This halves LDS-pipe traffic (96->48 KB/block-iter), the R3 bottleneck.
// Output written with nontemporal stores to avoid evicting B from L2.

#define MROWS 16384
#define NCOLS 2048
#define DDIM  1024
#define BM 128
#define BN 128
#define BK 64

typedef unsigned short u16;
typedef unsigned int   u32;
typedef __attribute__((ext_vector_type(8))) short          short8;
typedef __attribute__((ext_vector_type(8))) unsigned short ushort8;
typedef __attribute__((ext_vector_type(4))) float          float4v;

__device__ __forceinline__ u16 f32_to_bf16_rne(float f) {
  u32 u = __float_as_uint(f);
  u32 r = u + 0x7FFFu + ((u >> 16) & 1u);   // round-to-nearest-even
  return (u16)(r >> 16);
}

// One WAVE per row: convert 1024 floats -> bf16 (16B stores) + exact fp32 norm.
__global__ void prep_all(const float* __restrict__ feat, const float* __restrict__ cent,
                         u16* __restrict__ Ab, u16* __restrict__ Bb,
                         float* __restrict__ asq, float* __restrict__ bsq) {
  const int lane = threadIdx.x & 63;
  const int row  = (blockIdx.x * blockDim.x + threadIdx.x) >> 6;  // global wave id
  const float* src; u16* dst; float* sq;
  if (row < MROWS) {
    src = feat + (size_t)row * DDIM; dst = Ab + (size_t)row * DDIM; sq = asq + row;
  } else {
    const int r = row - MROWS;
    src = cent + (size_t)r * DDIM;   dst = Bb + (size_t)r * DDIM;  sq = bsq + r;
  }
  float s = 0.f;
  #pragma unroll
  for (int h = 0; h < 2; ++h) {
    const int base = h * 512 + lane * 8;          // 8 consecutive floats per lane
    const float4v v0 = *(const float4v*)(src + base);
    const float4v v1 = *(const float4v*)(src + base + 4);
    ushort8 o;
    o[0] = f32_to_bf16_rne(v0[0]); o[1] = f32_to_bf16_rne(v0[1]);
    o[2] = f32_to_bf16_rne(v0[2]); o[3] = f32_to_bf16_rne(v0[3]);
    o[4] = f32_to_bf16_rne(v1[0]); o[5] = f32_to_bf16_rne(v1[1]);
    o[6] = f32_to_bf16_rne(v1[2]); o[7] = f32_to_bf16_rne(v1[3]);
    *(ushort8*)(dst + base) = o;                  // 16B store
    s += v0[0]*v0[0] + v0[1]*v0[1] + v0[2]*v0[2] + v0[3]*v0[3]
       + v1[0]*v1[0] + v1[1]*v1[1] + v1[2]*v1[2] + v1[3]*v1[3];
  }
  #pragma unroll
  for (int off = 32; off > 0; off >>= 1) s += __shfl_down(s, off, 64);
  if (lane == 0) *sq = s;
}

__device__ __forceinline__ void load_lds16(const u16* g, u16* l) {
  __builtin_amdgcn_global_load_lds(
      (const __attribute__((address_space(1))) u32*)g,
      (__attribute__((address_space(3))) u32*)l, 16, 0, 0);
}

// C = A[M,D] * B[K,D]^T, epilogue dist = asq[m] + bsq[n] - 2*C.
// sA: 128 rows x 64 bf16 (128 B = one bank sweep per row); 16B chunk kc of
// row r stored at physical chunk kc ^ (r&7) -> conflict-free frag reads.
// B fragments: direct global->register loads, 16 fully-used 64B lines per
// instruction, served from L2 (B panel working set 4MB/XCD).
__global__ void dist_gemm(const u16* __restrict__ A, const u16* __restrict__ B,
                          const float* __restrict__ asq, const float* __restrict__ bsq,
                          float* __restrict__ out) {
  __shared__ __align__(16) u16 sA[BM * BK];   // 16 KB (B no longer staged)

  const int tid  = threadIdx.x;
  const int lane = tid & 63;
  const int wave = tid >> 6;        // 0..3
  const int quad = lane >> 4;       // 0..3
  const int l16  = lane & 15;
  const int sw   = l16 & 7;         // read-swizzle term (row&7 == l16&7)
  const int waveM = wave >> 1;      // 0..1
  const int waveN = wave & 1;       // 0..1

  // XCD-aware remap: all 16 col-blocks of a row-panel on one XCD (A hot in L2).
  const int l   = blockIdx.y * gridDim.x + blockIdx.x;  // 0..2047
  const int xcd = l & 7;
  const int j   = l >> 3;                               // 0..255
  const int by  = xcd * 16 + (j >> 4);                  // row panel
  const int bx  = j & 15;                               // col panel (fastest)
  const int rowBase = by * BM;
  const int colBase = bx * BN;

  // Per-lane B fragment base: row = colBase + waveN*64 + l16, k chunk = quad.
  const u16* Bp = B + (size_t)(colBase + waveN * 64 + l16) * DDIM + quad * 8;

  float4v acc[4][4];
  #pragma unroll
  for (int i = 0; i < 4; ++i)
    #pragma unroll
    for (int jj = 0; jj < 4; ++jj)
      acc[i][jj] = (float4v)(0.0f);

  for (int k0 = 0; k0 < DDIM; k0 += BK) {
    // B frags first: their L2 latency hides under A-staging + barrier drain.
    short8 b[2][4];
    #pragma unroll
    for (int g = 0; g < 2; ++g)
      #pragma unroll
      for (int jj = 0; jj < 4; ++jj)
        b[g][jj] = *(const short8*)(Bp + k0 + g * 32 + jj * 16 * DDIM);

    // A staging: 1024 chunks of 16B, 4/thread, lane-contiguous LDS dest.
    #pragma unroll
    for (int p = 0; p < 4; ++p) {
      const int c  = p * 256 + tid;             // LDS chunk index
      const int r  = c >> 3;                    // row 0..127
      const int kc = (c & 7) ^ (r & 7);         // swizzled global 16B-chunk
      load_lds16(A + (size_t)(rowBase + r) * DDIM + k0 + kc * 8, sA + c * 8);
    }
    __syncthreads();

    #pragma unroll
    for (int g = 0; g < 2; ++g) {
      short8 a[4];
      const int kchunk = g * 4 + quad;          // logical 16B chunk in row
      #pragma unroll
      for (int i = 0; i < 4; ++i) {
        const int rowA = waveM * 64 + i * 16 + l16;
        a[i] = *(const short8*)&sA[(rowA * 8 + (kchunk ^ sw)) * 8];
      }
      #pragma unroll
      for (int i = 0; i < 4; ++i)
        #pragma unroll
        for (int jj = 0; jj < 4; ++jj)
          acc[i][jj] = __builtin_amdgcn_mfma_f32_16x16x32_bf16(a[i], b[g][jj], acc[i][jj], 0, 0, 0);
    }
    __syncthreads();
  }

  // Epilogue. C/D layout: col = lane&15, row = quad*4 + reg (m89/m91).
  // Nontemporal stores: output is never re-read; keep B resident in L2.
  #pragma unroll
  for (int i = 0; i < 4; ++i) {
    #pragma unroll
    for (int jj = 0; jj < 4; ++jj) {
      const int col = colBase + waveN * 64 + jj * 16 + l16;
      const float bs = bsq[col];
      #pragma unroll
      for (int r = 0; r < 4; ++r) {
        const int row = rowBase + waveM * 64 + i * 16 + quad * 4 + r;
        __builtin_nontemporal_store(asq[row] + bs - 2.0f * acc[i][jj][r],
                                    out + (size_t)row * NCOLS + col);
      }
    }
  }
}

// Safety net only (ws too small): plain fp32, correct but slow.
__global__ void naive_dist(const float* __restrict__ feat, const float* __restrict__ cent,
                           float* __restrict__ out) {
  const int k = blockIdx.x * 16 + threadIdx.x;
  const int n = blockIdx.y * 16 + threadIdx.y;
  const float* fp = feat + (size_t)n * DDIM;
  const float* cp = cent + (size_t)k * DDIM;
  float s = 0.f;
  for (int d = 0; d < DDIM; ++d) { float df = fp[d] - cp[d]; s += df * df; }
  out[(size_t)n * NCOLS + k] = s;
}

extern "C" void kernel_launch(void* const* d_in, const int* in_sizes, int n_in,
                              void* d_out, int out_size, void* d_ws, size_t ws_size,
                              hipStream_t stream) {
  const float* feat    = (const float*)d_in[0];   // [16384, 1024]
  const float* centers = (const float*)d_in[1];   // [2048, 1024]
  float* out = (float*)d_out;                     // [16384, 2048]

  const size_t offA   = 0;
  const size_t offB   = (size_t)MROWS * DDIM * 2;            // 33,554,432
  const size_t offAsq = offB + (size_t)NCOLS * DDIM * 2;     // 37,748,736
  const size_t offBsq = offAsq + (size_t)MROWS * 4;          // 37,814,272
  const size_t need   = offBsq + (size_t)NCOLS * 4;          // ~37.8 MB

  if (ws_size < need) {
    dim3 grid(NCOLS / 16, MROWS / 16), block(16, 16);
    naive_dist<<<grid, block, 0, stream>>>(feat, centers, out);
    return;
  }

  u16*   Ab  = (u16*)((char*)d_ws + offA);
  u16*   Bb  = (u16*)((char*)d_ws + offB);
  float* asq = (float*)((char*)d_ws + offAsq);
  float* bsq = (float*)((char*)d_ws + offBsq);

  prep_all<<<(MROWS + NCOLS) / 4, 256, 0, stream>>>(feat, centers, Ab, Bb, asq, bsq);

  dim3 grid(NCOLS / BN, MROWS / BM);   // (16, 128)
  dist_gemm<<<grid, 256, 0, stream>>>(Ab, Bb, asq, bsq, out);
}

// Round 5
// 259.419 us; speedup vs baseline: 1.2239x; 1.2239x over previous
//
#include <hip/hip_runtime.h>

// dist[N,K] = ||feat_n||^2 + ||cent_k||^2 - 2 feat . cent
// N=16384, K=2048, D=1024, fp32 in/out.
// bf16 MFMA GEMM: 128x128 tile, BK=64, BOTH tiles staged via global_load_lds
// (16B) with XOR bank swizzle (R3 structure — R4's B-direct-load + nt-store
// experiment regressed 2x and is reverted). This round: 32x32x16 MFMA
// (half the MFMA instructions, 2382 vs 2075 TF ceiling, full-128B-line
// epilogue stores).

#define MROWS 16384
#define NCOLS 2048
#define DDIM  1024
#define BM 128
#define BN 128
#define BK 64

typedef unsigned short u16;
typedef unsigned int   u32;
typedef __attribute__((ext_vector_type(8)))  short          short8;
typedef __attribute__((ext_vector_type(8)))  unsigned short ushort8;
typedef __attribute__((ext_vector_type(4)))  float          float4v;
typedef __attribute__((ext_vector_type(16))) float          float16v;

__device__ __forceinline__ u16 f32_to_bf16_rne(float f) {
  u32 u = __float_as_uint(f);
  u32 r = u + 0x7FFFu + ((u >> 16) & 1u);   // round-to-nearest-even
  return (u16)(r >> 16);
}

// One WAVE per row: convert 1024 floats -> bf16 (16B stores) + exact fp32 norm.
__global__ void prep_all(const float* __restrict__ feat, const float* __restrict__ cent,
                         u16* __restrict__ Ab, u16* __restrict__ Bb,
                         float* __restrict__ asq, float* __restrict__ bsq) {
  const int lane = threadIdx.x & 63;
  const int row  = (blockIdx.x * blockDim.x + threadIdx.x) >> 6;  // global wave id
  const float* src; u16* dst; float* sq;
  if (row < MROWS) {
    src = feat + (size_t)row * DDIM; dst = Ab + (size_t)row * DDIM; sq = asq + row;
  } else {
    const int r = row - MROWS;
    src = cent + (size_t)r * DDIM;   dst = Bb + (size_t)r * DDIM;  sq = bsq + r;
  }
  float s = 0.f;
  #pragma unroll
  for (int h = 0; h < 2; ++h) {
    const int base = h * 512 + lane * 8;          // 8 consecutive floats per lane
    const float4v v0 = *(const float4v*)(src + base);
    const float4v v1 = *(const float4v*)(src + base + 4);
    ushort8 o;
    o[0] = f32_to_bf16_rne(v0[0]); o[1] = f32_to_bf16_rne(v0[1]);
    o[2] = f32_to_bf16_rne(v0[2]); o[3] = f32_to_bf16_rne(v0[3]);
    o[4] = f32_to_bf16_rne(v1[0]); o[5] = f32_to_bf16_rne(v1[1]);
    o[6] = f32_to_bf16_rne(v1[2]); o[7] = f32_to_bf16_rne(v1[3]);
    *(ushort8*)(dst + base) = o;                  // 16B store
    s += v0[0]*v0[0] + v0[1]*v0[1] + v0[2]*v0[2] + v0[3]*v0[3]
       + v1[0]*v1[0] + v1[1]*v1[1] + v1[2]*v1[2] + v1[3]*v1[3];
  }
  #pragma unroll
  for (int off = 32; off > 0; off >>= 1) s += __shfl_down(s, off, 64);
  if (lane == 0) *sq = s;
}

__device__ __forceinline__ void load_lds16(const u16* g, u16* l) {
  __builtin_amdgcn_global_load_lds(
      (const __attribute__((address_space(1))) u32*)g,
      (__attribute__((address_space(3))) u32*)l, 16, 0, 0);
}

// C = A[M,D] * B[K,D]^T, epilogue dist = asq[m] + bsq[n] - 2*C.
// LDS: 128 rows x 64 bf16 per tile; 16B chunk kc of row r stored at physical
// chunk kc ^ (r&7) -> conflict-free fragment reads (0 conflicts measured
// R2/R3). Staging permutes the SOURCE chunk so the LDS destination stays
// lane-contiguous (global_load_lds requirement).
// Wave grid 2x2, each wave = 64x64 via 2x2 of 32x32x16 MFMA tiles.
// A-frag layout: m = lane&31, k = (lane>>5)*8 + j (16B per lane).
// C/D layout (m74/m101): col = lane&31, row = (reg&3)+8*(reg>>2)+4*(lane>>5).
__global__ void dist_gemm(const u16* __restrict__ A, const u16* __restrict__ B,
                          const float* __restrict__ asq, const float* __restrict__ bsq,
                          float* __restrict__ out) {
  __shared__ __align__(16) u16 sA[BM * BK];   // 16 KB
  __shared__ __align__(16) u16 sB[BN * BK];   // 16 KB

  const int tid  = threadIdx.x;
  const int lane = tid & 63;
  const int wave = tid >> 6;        // 0..3
  const int m32  = lane & 31;       // row-within-32 for 32x32 MFMA
  const int half = lane >> 5;       // 0..1, k-half selector
  const int sw   = m32 & 7;         // read-swizzle term (row&7 == m32&7)
  const int waveM = wave >> 1;      // 0..1
  const int waveN = wave & 1;       // 0..1

  // XCD-aware remap: all 16 col-blocks of a row-panel on one XCD.
  const int l   = blockIdx.y * gridDim.x + blockIdx.x;  // 0..2047
  const int xcd = l & 7;
  const int j   = l >> 3;                               // 0..255
  const int by  = xcd * 16 + (j >> 4);                  // row panel
  const int bx  = j & 15;                               // col panel (fastest)
  const int rowBase = by * BM;
  const int colBase = bx * BN;

  float16v acc[2][2];
  #pragma unroll
  for (int i = 0; i < 2; ++i)
    #pragma unroll
    for (int jj = 0; jj < 2; ++jj)
      acc[i][jj] = (float16v)(0.0f);

  for (int k0 = 0; k0 < DDIM; k0 += BK) {
    // 1024 chunks of 16B per tile; 4 chunks/thread/tile, lane-contiguous LDS.
    #pragma unroll
    for (int p = 0; p < 4; ++p) {
      const int c  = p * 256 + tid;             // LDS chunk index
      const int r  = c >> 3;                    // row 0..127
      const int kc = (c & 7) ^ (r & 7);         // swizzled global 16B-chunk
      load_lds16(A + (size_t)(rowBase + r) * DDIM + k0 + kc * 8, sA + c * 8);
      load_lds16(B + (size_t)(colBase + r) * DDIM + k0 + kc * 8, sB + c * 8);
    }
    __syncthreads();

    // 4 k-groups of 16 within the 64-k tile: 16 MFMAs (32x32x16) per iter.
    #pragma unroll
    for (int g = 0; g < 4; ++g) {
      short8 a[2], b[2];
      const int kchunk = g * 2 + half;          // logical 16B chunk in row
      #pragma unroll
      for (int t = 0; t < 2; ++t) {
        const int rowA = waveM * 64 + t * 32 + m32;
        a[t] = *(const short8*)&sA[(rowA * 8 + (kchunk ^ sw)) * 8];
        const int rowB = waveN * 64 + t * 32 + m32;
        b[t] = *(const short8*)&sB[(rowB * 8 + (kchunk ^ sw)) * 8];
      }
      #pragma unroll
      for (int ti = 0; ti < 2; ++ti)
        #pragma unroll
        for (int tj = 0; tj < 2; ++tj)
          acc[ti][tj] = __builtin_amdgcn_mfma_f32_32x32x16_bf16(a[ti], b[tj], acc[ti][tj], 0, 0, 0);
    }
    __syncthreads();
  }

  // Epilogue. 32x32 C/D: col = lane&31, row = (reg&3)+8*(reg>>2)+4*half.
  // Per (ti,tj,reg) store: 64 lanes cover 2 rows x 128B full lines.
  #pragma unroll
  for (int ti = 0; ti < 2; ++ti) {
    #pragma unroll
    for (int tj = 0; tj < 2; ++tj) {
      const int col = colBase + waveN * 64 + tj * 32 + m32;
      const float bs = bsq[col];
      #pragma unroll
      for (int reg = 0; reg < 16; ++reg) {
        const int row = rowBase + waveM * 64 + ti * 32
                      + (reg & 3) + 8 * (reg >> 2) + 4 * half;
        out[(size_t)row * NCOLS + col] = asq[row] + bs - 2.0f * acc[ti][tj][reg];
      }
    }
  }
}

// Safety net only (ws too small): plain fp32, correct but slow.
__global__ void naive_dist(const float* __restrict__ feat, const float* __restrict__ cent,
                           float* __restrict__ out) {
  const int k = blockIdx.x * 16 + threadIdx.x;
  const int n = blockIdx.y * 16 + threadIdx.y;
  const float* fp = feat + (size_t)n * DDIM;
  const float* cp = cent + (size_t)k * DDIM;
  float s = 0.f;
  for (int d = 0; d < DDIM; ++d) { float df = fp[d] - cp[d]; s += df * df; }
  out[(size_t)n * NCOLS + k] = s;
}

extern "C" void kernel_launch(void* const* d_in, const int* in_sizes, int n_in,
                              void* d_out, int out_size, void* d_ws, size_t ws_size,
                              hipStream_t stream) {
  const float* feat    = (const float*)d_in[0];   // [16384, 1024]
  const float* centers = (const float*)d_in[1];   // [2048, 1024]
  float* out = (float*)d_out;                     // [16384, 2048]

  const size_t offA   = 0;
  const size_t offB   = (size_t)MROWS * DDIM * 2;            // 33,554,432
  const size_t offAsq = offB + (size_t)NCOLS * DDIM * 2;     // 37,748,736
  const size_t offBsq = offAsq + (size_t)MROWS * 4;          // 37,814,272
  const size_t need   = offBsq + (size_t)NCOLS * 4;          // ~37.8 MB

  if (ws_size < need) {
    dim3 grid(NCOLS / 16, MROWS / 16), block(16, 16);
    naive_dist<<<grid, block, 0, stream>>>(feat, centers, out);
    return;
  }

  u16*   Ab  = (u16*)((char*)d_ws + offA);
  u16*   Bb  = (u16*)((char*)d_ws + offB);
  float* asq = (float*)((char*)d_ws + offAsq);
  float* bsq = (float*)((char*)d_ws + offBsq);

  prep_all<<<(MROWS + NCOLS) / 4, 256, 0, stream>>>(feat, centers, Ab, Bb, asq, bsq);

  dim3 grid(NCOLS / BN, MROWS / BM);   // (16, 128)
  dist_gemm<<<grid, 256, 0, stream>>>(Ab, Bb, asq, bsq, out);
}